// Round 7
// baseline (630.237 us; speedup 1.0000x reference)
//
#include <hip/hip_runtime.h>
#include <hip/hip_cooperative_groups.h>
#include <stdint.h>

namespace cg = cooperative_groups;
typedef int v4i __attribute__((ext_vector_type(4)));

// Problem constants
constexpr int C     = 256;           // channels (in == out)
constexpr int H     = 28, W = 28;
constexpr int HW    = H * W;         // 784
constexpr int NB    = 64;            // batch
constexpr int GP    = NB * HW;       // 50176 flattened pixels
constexpr int CNT   = GP;            // per-channel reduction count
constexpr int TOTAL = NB * C * HW;   // 12,845,056
constexpr int MT    = 64;            // pixels per block (M-tile)
constexpr int NBLK  = GP / MT;       // 784 conv tiles, exact
constexpr int LROWS = 128;           // staged pixel rows: gp0-32 .. gp0+95
constexpr int GPB   = GP / 256;      // 196 pixel-blocks per channel-chunk
constexpr int CGRID = 768;           // cooperative grid (256 CU x 3 blocks)

// ---------------------------------------------------------------------------
// Shared device helpers (used by both the fused cooperative kernel and the
// 5-dispatch fallback path).
// Frag order (A and B identical) for mfma_i32_16x16x64_i8: lane l holds
// ch = g*16 + (l&15), k = (l>>4)*16+e. wbf[((tp*4+kb)*16+g)*64+l].
// +1 -> 0x01, -1 -> 0xFF, zero-pad = 0x00.
// ---------------------------------------------------------------------------
__device__ __forceinline__ void pack_w_item(int gid, const float* __restrict__ pw1,
                                            const float* __restrict__ pw2,
                                            v4i* __restrict__ wbf1, v4i* __restrict__ wbf2) {
    const bool second = (gid >= 36864);
    const float* w = second ? pw2 : pw1;
    v4i* dst       = second ? wbf2 : wbf1;
    const int idx = second ? gid - 36864 : gid;   // ((tp*4+kb)*16+g)*64+l
    const int l  = idx & 63;
    const int g  = (idx >> 6) & 15;
    const int kb = (idx >> 10) & 3;
    const int tp = idx >> 12;          // 0..8
    const int co  = g * 16 + (l & 15);
    const int ci0 = kb * 64 + (l >> 4) * 16;
    int b0 = 0, b1 = 0, b2 = 0, b3 = 0;
#pragma unroll
    for (int e = 0; e < 16; ++e) {
        float v = w[((size_t)co * C + ci0 + e) * 9 + tp];
        int b = (v < 0.f) ? 0xFF : 0x01;
        int sh = (e & 3) * 8;
        if (e < 4) b0 |= b << sh; else if (e < 8) b1 |= b << sh;
        else if (e < 12) b2 |= b << sh; else b3 |= b << sh;
    }
    v4i o; o.x = b0; o.y = b1; o.z = b2; o.w = b3;
    dst[idx] = o;
}

__device__ __forceinline__ void pack_x_item(int local, int t, const float* __restrict__ x,
                                            v4i* __restrict__ xb, double* __restrict__ stats) {
    const int ch = local / GPB;
    const int gp = (local % GPB) * 256 + t;
    if (ch == 0 && gp < 1024) stats[gp] = 0.0;   // zero sum1/sumsq1/sum2/sumsq2
    const int n = gp / HW, p = gp % HW;
    const float* base = x + (size_t)n * C * HW + p + (size_t)(ch * 16) * HW;
    int b0 = 0, b1 = 0, b2 = 0, b3 = 0;
#pragma unroll
    for (int e = 0; e < 16; ++e) {
        float v = base[(size_t)e * HW];
        int b = (v < 0.f) ? 0xFF : 0x01;
        int sh = (e & 3) * 8;
        if (e < 4) b0 |= b << sh; else if (e < 8) b1 |= b << sh;
        else if (e < 12) b2 |= b << sh; else b3 |= b << sh;
    }
    v4i o; o.x = b0; o.y = b1; o.z = b2; o.w = b3;
    xb[(size_t)ch * GP + gp] = o;
}

__device__ __forceinline__ void finalize_coefs(int t, const double* __restrict__ sum,
                                               const double* __restrict__ sumsq,
                                               const float* __restrict__ gamma,
                                               const float* __restrict__ beta,
                                               float* __restrict__ s_scale,
                                               float* __restrict__ s_shift) {
    double mean = sum[t] / (double)CNT;
    double var  = sumsq[t] / (double)CNT - mean * mean;
    double inv  = 1.0 / sqrt(var + 1e-5);
    s_scale[t] = (float)inv * gamma[t];
    s_shift[t] = beta[t] - (float)(mean * inv) * gamma[t];
}

__device__ __forceinline__ void signpack_item(int local, int t, const short* __restrict__ y,
                                              const float* __restrict__ s_scale,
                                              const float* __restrict__ s_shift,
                                              v4i* __restrict__ xb) {
    const int ch = local / GPB;
    const int gp = (local % GPB) * 256 + t;
    const int n = gp / HW, p = gp % HW;
    const short* base = y + (size_t)n * C * HW + p + (size_t)(ch * 16) * HW;
    int b0 = 0, b1 = 0, b2 = 0, b3 = 0;
#pragma unroll
    for (int e = 0; e < 16; ++e) {
        const int c = ch * 16 + e;
        float z = (float)base[(size_t)e * HW] * s_scale[c] + s_shift[c];
        int b = (z < 0.f) ? 0xFF : 0x01;
        int sh = (e & 3) * 8;
        if (e < 4) b0 |= b << sh; else if (e < 8) b1 |= b << sh;
        else if (e < 12) b2 |= b << sh; else b3 |= b << sh;
    }
    v4i o; o.x = b0; o.y = b1; o.z = b2; o.w = b3;
    xb[(size_t)ch * GP + gp] = o;
}

__device__ __forceinline__ void clip_loop(int start, int stride, const float4* __restrict__ z4,
                                          const float* __restrict__ s_scale,
                                          const float* __restrict__ s_shift,
                                          float4* __restrict__ out4) {
    for (int i = start; i < TOTAL / 4; i += stride) {
        int c = (i / (HW / 4)) & (C - 1);
        float s = s_scale[c], b = s_shift[c];
        float4 v = z4[i];
        v.x = fminf(1.f, fmaxf(-1.f, v.x * s + b));
        v.y = fminf(1.f, fmaxf(-1.f, v.y * s + b));
        v.z = fminf(1.f, fmaxf(-1.f, v.z * s + b));
        v.w = fminf(1.f, fmaxf(-1.f, v.w * s + b));
        out4[i] = v;
    }
}

// ---------------------------------------------------------------------------
// Conv tile: implicit-GEMM i8 MFMA, software-pipelined ping-pong (R9/R11
// structure — best measured 54 us/conv, MfmaUtil 21.6). Unchanged internals.
// ---------------------------------------------------------------------------

#define ACC_DECL v4i c00={0,0,0,0},c01={0,0,0,0},c02={0,0,0,0},c03={0,0,0,0}, \
                     c10={0,0,0,0},c11={0,0,0,0},c12={0,0,0,0},c13={0,0,0,0}, \
                     c20={0,0,0,0},c21={0,0,0,0},c22={0,0,0,0},c23={0,0,0,0}, \
                     c30={0,0,0,0},c31={0,0,0,0},c32={0,0,0,0},c33={0,0,0,0};

#define MFMA(a,b,c) c = __builtin_amdgcn_mfma_i32_16x16x64_i8(a, b, c, 0, 0, 0);

#define B_LOADQ(P, idx) { const v4i* bp = wbf + (idx); \
    P##0 = bp[0]; P##1 = bp[64]; P##2 = bp[128]; P##3 = bp[192]; }

#define A_READQ(P, cb) { \
    P##0 = xl[R0 + ((cb) ^ S0)]; P##1 = xl[R1 + ((cb) ^ S1)]; \
    P##2 = xl[R2 + ((cb) ^ S2)]; P##3 = xl[R3 + ((cb) ^ S3)]; }

#define MFMA_Q(A,B) \
    __builtin_amdgcn_s_setprio(1); \
    MFMA(A##0,B##0,c00) MFMA(A##1,B##0,c10) MFMA(A##2,B##0,c20) MFMA(A##3,B##0,c30) \
    MFMA(A##0,B##1,c01) MFMA(A##1,B##1,c11) MFMA(A##2,B##1,c21) MFMA(A##3,B##1,c31) \
    MFMA(A##0,B##2,c02) MFMA(A##1,B##2,c12) MFMA(A##2,B##2,c22) MFMA(A##3,B##2,c32) \
    MFMA(A##0,B##3,c03) MFMA(A##1,B##3,c13) MFMA(A##2,B##3,c23) MFMA(A##3,B##3,c33) \
    __builtin_amdgcn_s_setprio(0);

#define TAPVARS(TPX, RD0,RD1,RD2,RD3, SD0,SD1,SD2,SD3) { \
    const int dr = (TPX)/3 - 1, dc = (TPX)%3 - 1; \
    const int lrb = 32 + llo + dr * W + dc; \
    const int sm = lrb & 15; \
    const bool m0 = ((unsigned)(cm0+dc) < 28u) && ((unsigned)(rm0+dr) < 28u); \
    const bool m1 = ((unsigned)(cm1+dc) < 28u) && ((unsigned)(rm1+dr) < 28u); \
    const bool m2 = ((unsigned)(cm2+dc) < 28u) && ((unsigned)(rm2+dr) < 28u); \
    const bool m3 = ((unsigned)(cm3+dc) < 28u) && ((unsigned)(rm3+dr) < 28u); \
    RD0 = m0 ? lrb*16        : 2048; SD0 = m0 ? sm : 0; \
    RD1 = m1 ? lrb*16 + 256  : 2048; SD1 = m1 ? sm : 0; \
    RD2 = m2 ? lrb*16 + 512  : 2048; SD2 = m2 ? sm : 0; \
    RD3 = m3 ? lrb*16 + 768  : 2048; SD3 = m3 ? sm : 0; }

#define EPIV(mt,ntl) { \
    const int gpv = gp0 + (mt)*16 + lhi*4; \
    const int nn = gpv / HW; const int pp = gpv - nn*HW; \
    const size_t base = (size_t)nn*(C*HW) + (size_t)(wn*64+(ntl)*16+llo)*HW + pp; \
    const v4i cc = c##mt##ntl; \
    if constexpr (HAS_RES) { \
        const float4 r = *(const float4*)(residual + base); \
        float4 o; o.x = (float)cc.x + r.x; o.y = (float)cc.y + r.y; \
        o.z = (float)cc.z + r.z; o.w = (float)cc.w + r.w; \
        *(float4*)((float*)yout + base) = o; \
        sy##ntl += o.x + o.y + o.z + o.w; \
        sq##ntl += o.x*o.x + o.y*o.y + o.z*o.z + o.w*o.w; \
    } else { \
        int2 o; o.x = (cc.x & 0xFFFF) | (cc.y << 16); \
        o.y = (cc.z & 0xFFFF) | (cc.w << 16); \
        *(int2*)((short*)yout + base) = o; \
        const float fx = (float)cc.x, fy = (float)cc.y, fz = (float)cc.z, fw = (float)cc.w; \
        sy##ntl += fx + fy + fz + fw; \
        sq##ntl += fx*fx + fy*fy + fz*fz + fw*fw; \
    } }

#define REDN(ntl) { float s1 = sy##ntl, s2 = sq##ntl; \
    s1 += __shfl_down(s1, 32); s1 += __shfl_down(s1, 16); \
    s2 += __shfl_down(s2, 32); s2 += __shfl_down(s2, 16); \
    if (l < 16) { const int co = wn*64 + (ntl)*16 + l; \
        atomicAdd(&sum[co], (double)s1); atomicAdd(&sumsq[co], (double)s2); } }

template<bool HAS_RES, typename OUT_T>
__device__ __forceinline__ void conv_tile(const int tile, const int t,
                                          v4i* __restrict__ xl,
                                          const v4i* __restrict__ xb,
                                          const v4i* __restrict__ wbf,
                                          const float* __restrict__ residual,
                                          OUT_T* __restrict__ yout,
                                          double* __restrict__ sum,
                                          double* __restrict__ sumsq) {
    const int gp0 = tile * MT;
    __syncthreads();                        // xl reuse guard (phases / 2nd tile)

    // stage 128 pixel-rows x 16 chunks, coalesced reads, swizzled LDS writes
#pragma unroll
    for (int pass = 0; pass < 8; ++pass) {
        const int i = pass * 256 + t;
        const int c = i >> 7;               // plane 0..15
        const int r = i & 127;              // local row
        int gsrc = min(max(gp0 - 32 + r, 0), GP - 1);
        xl[r * 16 + (c ^ (r & 15))] = xb[(size_t)c * GP + gsrc];
    }
    if (t < 16) { v4i z = {0,0,0,0}; xl[LROWS * 16 + t] = z; }   // zero row
    __syncthreads();

    const int l = t & 63, wn = t >> 6;
    const int llo = l & 15, lhi = l >> 4;

    const int gx0 = gp0 + llo, gx1 = gx0 + 16, gx2 = gx0 + 32, gx3 = gx0 + 48;
    const int pm0 = gx0 % HW, pm1 = gx1 % HW, pm2 = gx2 % HW, pm3 = gx3 % HW;
    const int rm0 = pm0 / W, rm1 = pm1 / W, rm2 = pm2 / W, rm3 = pm3 / W;
    const int cm0 = pm0 % W, cm1 = pm1 % W, cm2 = pm2 % W, cm3 = pm3 % W;

    ACC_DECL
    const int bw = wn * 256 + l;

    int R0, R1, R2, R3, S0, S1, S2, S3;
    TAPVARS(0, R0,R1,R2,R3, S0,S1,S2,S3)
    v4i bP0,bP1,bP2,bP3, bQ0,bQ1,bQ2,bQ3;
    v4i aP0,aP1,aP2,aP3, aQ0,aQ1,aQ2,aQ3;
    B_LOADQ(bP, bw)                 // (tap0, kb0)
    A_READQ(aP, lhi)

#pragma unroll 1
    for (int tp = 0; tp < 9; ++tp) {
        const int tb = bw + tp * 4096;
        B_LOADQ(bQ, tb + 1024)
        A_READQ(aQ, 4 + lhi)
        MFMA_Q(aP, bP)
        B_LOADQ(bP, tb + 2048)
        A_READQ(aP, 8 + lhi)
        MFMA_Q(aQ, bQ)
        B_LOADQ(bQ, tb + 3072)
        A_READQ(aQ, 12 + lhi)
        MFMA_Q(aP, bP)
        const int tpn = (tp < 8) ? tp + 1 : 8;
        int N0, N1, N2, N3, T0, T1, T2, T3;
        TAPVARS(tpn, N0,N1,N2,N3, T0,T1,T2,T3)
        B_LOADQ(bP, bw + tpn * 4096)
        { aP0 = xl[N0 + (lhi ^ T0)]; aP1 = xl[N1 + (lhi ^ T1)];
          aP2 = xl[N2 + (lhi ^ T2)]; aP3 = xl[N3 + (lhi ^ T3)]; }
        MFMA_Q(aQ, bQ)
        R0 = N0; R1 = N1; R2 = N2; R3 = N3;
        S0 = T0; S1 = T1; S2 = T2; S3 = T3;
    }

    float sy0 = 0, sy1 = 0, sy2 = 0, sy3 = 0;
    float sq0 = 0, sq1 = 0, sq2 = 0, sq3 = 0;
    EPIV(0,0) EPIV(0,1) EPIV(0,2) EPIV(0,3)
    EPIV(1,0) EPIV(1,1) EPIV(1,2) EPIV(1,3)
    EPIV(2,0) EPIV(2,1) EPIV(2,2) EPIV(2,3)
    EPIV(3,0) EPIV(3,1) EPIV(3,2) EPIV(3,3)
    REDN(0) REDN(1) REDN(2) REDN(3)
}

// ---------------------------------------------------------------------------
// R12: cooperative mega-kernel — all 5 phases, 4 grid syncs, zero dispatch
// boundaries. R11 post-mortem: bconv x2 = 108 us but total 226; tail ideal
// ~35-50 us -> ~60-70 us of boundary/drain overhead. Persistent 768 blocks
// (3/CU; LDS 35 KB -> 4-block capacity, co-residency safe). Conv tiles
// 768..783 go to blocks {0,48,..,720} (distinct CUs under any sane mapping).
// ---------------------------------------------------------------------------
extern "C" __global__ void __launch_bounds__(256, 3)
fused_all(const float* __restrict__ x,
          const float* __restrict__ w1, const float* __restrict__ w2,
          const float* __restrict__ g1, const float* __restrict__ b1,
          const float* __restrict__ g2, const float* __restrict__ b2,
          float* __restrict__ out, float* __restrict__ z2,
          v4i* __restrict__ xb1, v4i* __restrict__ xb2,
          v4i* __restrict__ wbf1, v4i* __restrict__ wbf2,
          double* __restrict__ stats) {
    cg::grid_group grid = cg::this_grid();
    __shared__ v4i xl[LROWS * 16 + 16];          // 33,024 B
    __shared__ float s_scale[C], s_shift[C];     // 2,048 B
    const int t   = threadIdx.x;
    const int bid = blockIdx.x;
    const int nb  = gridDim.x;                   // CGRID
    double* sum1 = stats,       *sumsq1 = stats + 256;
    double* sum2 = stats + 512, *sumsq2 = stats + 768;
    short* y1 = (short*)out;                     // d_out scratch, overwritten in P4

    // ---- P0: weight packs + x pack + stats zero ----
    for (int vb = bid; vb < 288 + 16 * GPB; vb += nb) {
        if (vb < 288) pack_w_item(vb * 256 + t, w1, w2, wbf1, wbf2);
        else          pack_x_item(vb - 288, t, x, xb1, stats);
    }
    grid.sync();

    // ---- P1: conv1 (784 tiles) ----
    conv_tile<false, short>(bid, t, xl, xb1, wbf1, nullptr, y1, sum1, sumsq1);
    if ((bid % 48) == 0) conv_tile<false, short>(CGRID + bid / 48, t, xl, xb1, wbf1,
                                                 nullptr, y1, sum1, sumsq1);
    grid.sync();

    // ---- P2: finalize BN1 + signpack -> xb2 ----
    finalize_coefs(t, sum1, sumsq1, g1, b1, s_scale, s_shift);
    __syncthreads();
    for (int vb = bid; vb < 16 * GPB; vb += nb)
        signpack_item(vb, t, y1, s_scale, s_shift, xb2);
    grid.sync();

    // ---- P3: conv2 + residual (784 tiles) ----
    conv_tile<true, float>(bid, t, xl, xb2, wbf2, x, z2, sum2, sumsq2);
    if ((bid % 48) == 0) conv_tile<true, float>(CGRID + bid / 48, t, xl, xb2, wbf2,
                                                x, z2, sum2, sumsq2);
    grid.sync();

    // ---- P4: finalize BN2 + clip -> out ----
    finalize_coefs(t, sum2, sumsq2, g2, b2, s_scale, s_shift);
    __syncthreads();
    clip_loop(bid * 256 + t, nb * 256, (const float4*)z2, s_scale, s_shift, (float4*)out);
}

// ---------------------------------------------------------------------------
// Fallback path (5 dispatches, R11 behavior) — used only if cooperative
// launch is rejected.
// ---------------------------------------------------------------------------
__global__ void pack_all_kernel(const float* __restrict__ pw1, const float* __restrict__ pw2,
                                const float* __restrict__ x,
                                v4i* __restrict__ wbf1, v4i* __restrict__ wbf2,
                                v4i* __restrict__ xb, double* __restrict__ stats) {
    const int t = threadIdx.x, bid = blockIdx.x;
    if (bid < 288) pack_w_item(bid * 256 + t, pw1, pw2, wbf1, wbf2);
    else           pack_x_item(bid - 288, t, x, xb, stats);
}

__global__ void bn_signpack_kernel(const short* __restrict__ y,
                                   const double* __restrict__ sum,
                                   const double* __restrict__ sumsq,
                                   const float* __restrict__ gamma,
                                   const float* __restrict__ beta,
                                   v4i* __restrict__ xb) {
    __shared__ float s_scale[C], s_shift[C];
    const int t = threadIdx.x;
    finalize_coefs(t, sum, sumsq, gamma, beta, s_scale, s_shift);
    __syncthreads();
    signpack_item(blockIdx.x, t, y, s_scale, s_shift, xb);
}

template<bool HAS_RES, typename OUT_T>
__launch_bounds__(256, 3)
__global__ void bconv_mfma(const v4i* __restrict__ xb,
                           const v4i* __restrict__ wbf,
                           const float* __restrict__ residual,
                           OUT_T* __restrict__ yout,
                           double* __restrict__ sum, double* __restrict__ sumsq) {
    __shared__ v4i xl[LROWS * 16 + 16];
    conv_tile<HAS_RES, OUT_T>(blockIdx.x, threadIdx.x, xl, xb, wbf, residual, yout, sum, sumsq);
}

__global__ void bn_clip_kernel(const float4* __restrict__ z,
                               const double* __restrict__ sum,
                               const double* __restrict__ sumsq,
                               const float* __restrict__ gamma,
                               const float* __restrict__ beta,
                               float4* __restrict__ out) {
    __shared__ float s_scale[C], s_shift[C];
    const int t = threadIdx.x;
    finalize_coefs(t, sum, sumsq, gamma, beta, s_scale, s_shift);
    __syncthreads();
    clip_loop(blockIdx.x * 256 + t, gridDim.x * 256, z, s_scale, s_shift, out);
}

// ---------------------------------------------------------------------------
extern "C" void kernel_launch(void* const* d_in, const int* in_sizes, int n_in,
                              void* d_out, int out_size, void* d_ws, size_t ws_size,
                              hipStream_t stream) {
    const float* x  = (const float*)d_in[0];
    const float* w1 = (const float*)d_in[1];
    const float* w2 = (const float*)d_in[2];
    const float* g1 = (const float*)d_in[3];
    const float* b1 = (const float*)d_in[4];
    const float* g2 = (const float*)d_in[5];
    const float* b2 = (const float*)d_in[6];
    float* out = (float*)d_out;

    char* ws = (char*)d_ws;
    size_t off = 0;
    float* z2 = (float*)(ws + off);   off += (size_t)TOTAL * 4;        // 51.4 MB
    v4i* xb1  = (v4i*)(ws + off);     off += (size_t)GP * 16 * 16;     // 12.85 MB
    v4i* xb2  = (v4i*)(ws + off);     off += (size_t)GP * 16 * 16;     // 12.85 MB
    v4i* wbf1 = (v4i*)(ws + off);     off += (size_t)36864 * 16;       // 590 KB
    v4i* wbf2 = (v4i*)(ws + off);     off += (size_t)36864 * 16;
    double* stats = (double*)(ws + off); off += 4 * 256 * 8;
    double* sum1 = stats, *sumsq1 = stats + 256, *sum2 = stats + 512, *sumsq2 = stats + 768;
    short* y1 = (short*)d_out;

    void* kargs[] = {(void*)&x, (void*)&w1, (void*)&w2, (void*)&g1, (void*)&b1,
                     (void*)&g2, (void*)&b2, (void*)&out, (void*)&z2,
                     (void*)&xb1, (void*)&xb2, (void*)&wbf1, (void*)&wbf2,
                     (void*)&stats};
    hipError_t err = hipLaunchCooperativeKernel(reinterpret_cast<void*>(fused_all),
                                                dim3(CGRID), dim3(256), kargs, 0, stream);
    if (err != hipSuccess) {
        // fallback: 5-dispatch path (R11 behavior, 226 us)
        pack_all_kernel<<<288 + 16 * GPB, 256, 0, stream>>>(w1, w2, x, wbf1, wbf2, xb1, stats);
        bconv_mfma<false, short><<<NBLK, 256, 0, stream>>>(xb1, wbf1, nullptr, y1, sum1, sumsq1);
        bn_signpack_kernel<<<16 * GPB, 256, 0, stream>>>(y1, sum1, sumsq1, g1, b1, xb2);
        bconv_mfma<true, float><<<NBLK, 256, 0, stream>>>(xb2, wbf2, x, z2, sum2, sumsq2);
        bn_clip_kernel<<<4096, 256, 0, stream>>>((const float4*)z2, sum2, sumsq2, g2, b2,
                                                 (float4*)out);
    }
}

// Round 8
// 203.083 us; speedup vs baseline: 3.1033x; 3.1033x over previous
//
#include <hip/hip_runtime.h>
#include <stdint.h>

typedef int v4i __attribute__((ext_vector_type(4)));

// Problem constants
constexpr int C     = 256;           // channels (in == out)
constexpr int H     = 28, W = 28;
constexpr int HW    = H * W;         // 784
constexpr int NB    = 64;            // batch
constexpr int GP    = NB * HW;       // 50176 flattened pixels
constexpr int CNT   = GP;            // per-channel reduction count
constexpr int TOTAL = NB * C * HW;   // 12,845,056
constexpr int MT    = 112;           // pixels per block (R13: 64 -> 112)
constexpr int NBLK  = GP / MT;       // 448 conv tiles, exact
constexpr int LROWS = 176;           // staged rows: gp0-32 .. gp0+143
constexpr int ZROW  = LROWS * 16;    // zero-row base (v4i index)
constexpr int GPB   = GP / 256;      // 196 pixel-blocks per channel-chunk

// ---------------------------------------------------------------------------
// Helpers. Frag order (A and B identical) for mfma_i32_16x16x64_i8: lane l
// holds ch = g*16 + (l&15), k = (l>>4)*16+e. wbf[((tp*4+kb)*16+g)*64+l].
// +1 -> 0x01, -1 -> 0xFF, zero-pad = 0x00 (true zero padding, no P-table).
// ---------------------------------------------------------------------------
__device__ __forceinline__ void pack_x_item(int local, int t, const float* __restrict__ x,
                                            v4i* __restrict__ xb, double* __restrict__ stats) {
    const int ch = local / GPB;
    const int gp = (local % GPB) * 256 + t;
    if (ch == 0 && gp < 1024) stats[gp] = 0.0;   // zero sum1/sumsq1/sum2/sumsq2
    const int n = gp / HW, p = gp % HW;
    const float* base = x + (size_t)n * C * HW + p + (size_t)(ch * 16) * HW;
    int b0 = 0, b1 = 0, b2 = 0, b3 = 0;
#pragma unroll
    for (int e = 0; e < 16; ++e) {
        float v = base[(size_t)e * HW];
        int b = (v < 0.f) ? 0xFF : 0x01;
        int sh = (e & 3) * 8;
        if (e < 4) b0 |= b << sh; else if (e < 8) b1 |= b << sh;
        else if (e < 12) b2 |= b << sh; else b3 |= b << sh;
    }
    v4i o; o.x = b0; o.y = b1; o.z = b2; o.w = b3;
    xb[(size_t)ch * GP + gp] = o;
}

__device__ __forceinline__ void finalize_coefs(int t, const double* __restrict__ sum,
                                               const double* __restrict__ sumsq,
                                               const float* __restrict__ gamma,
                                               const float* __restrict__ beta,
                                               float* __restrict__ s_scale,
                                               float* __restrict__ s_shift) {
    double mean = sum[t] / (double)CNT;
    double var  = sumsq[t] / (double)CNT - mean * mean;
    double inv  = 1.0 / sqrt(var + 1e-5);
    s_scale[t] = (float)inv * gamma[t];
    s_shift[t] = beta[t] - (float)(mean * inv) * gamma[t];
}

// ---------------------------------------------------------------------------
// R13 pack_all: w-part rewritten as LDS transpose (32 blocks). Old version
// gathered 4 B/lane at 9.2 KB stride (fully scattered, latency-bound). New:
// stream the co-group's 147 KB coalesced (float4), sign-bytes to LDS, gather
// from LDS (fast), store coalesced 1 KB runs. x-part unchanged (3136 blocks).
// ---------------------------------------------------------------------------
__global__ void pack_all_kernel(const float* __restrict__ pw1, const float* __restrict__ pw2,
                                const float* __restrict__ x,
                                v4i* __restrict__ wbf1, v4i* __restrict__ wbf2,
                                v4i* __restrict__ xb, double* __restrict__ stats) {
    __shared__ signed char sgn[36864];     // 16 co x 2304 (ci,tap) sign bytes
    const int t = threadIdx.x;
    const int bid = blockIdx.x;
    if (bid < 32) {                        // (tensor, g): 2 x 16 co-groups
        const int g = bid & 15;
        const float* w = (bid >> 4) ? pw2 : pw1;
        v4i* dst       = (bid >> 4) ? wbf2 : wbf1;
        const float4* wg = (const float4*)(w + (size_t)g * 16 * 2304);
        int* sg4 = (int*)sgn;
        for (int pass = 0; pass < 36; ++pass) {        // 9216 float4 / 256
            const int m4 = pass * 256 + t;
            float4 v = wg[m4];
            int pk = (v.x < 0.f ? 0xFF : 0x01)
                   | ((v.y < 0.f ? 0xFF : 0x01) << 8)
                   | ((v.z < 0.f ? 0xFF : 0x01) << 16)
                   | ((v.w < 0.f ? 0xFF : 0x01) << 24);
            sg4[m4] = pk;
        }
        __syncthreads();
        const int l = t & 63, kb = t >> 6;
        const int colb = (l & 15) * 2304;              // co_local * 2304
        const int cib  = kb * 64 + (l >> 4) * 16;      // ci0
        for (int tp = 0; tp < 9; ++tp) {
            int b0 = 0, b1 = 0, b2 = 0, b3 = 0;
#pragma unroll
            for (int e = 0; e < 16; ++e) {
                int b = (int)(unsigned char)sgn[colb + (cib + e) * 9 + tp];
                int sh = (e & 3) * 8;
                if (e < 4) b0 |= b << sh; else if (e < 8) b1 |= b << sh;
                else if (e < 12) b2 |= b << sh; else b3 |= b << sh;
            }
            v4i o; o.x = b0; o.y = b1; o.z = b2; o.w = b3;
            dst[((tp * 4 + kb) * 16 + g) * 64 + l] = o;
        }
    } else {
        pack_x_item(bid - 32, t, x, xb, stats);
    }
}

// ---------------------------------------------------------------------------
// Fused finalize (redundant per block) + BN + binarize -> i8 plane-major.
// ---------------------------------------------------------------------------
__global__ void bn_signpack_kernel(const short* __restrict__ y,
                                   const double* __restrict__ sum,
                                   const double* __restrict__ sumsq,
                                   const float* __restrict__ gamma,
                                   const float* __restrict__ beta,
                                   v4i* __restrict__ xb) {
    __shared__ float s_scale[C], s_shift[C];
    const int t = threadIdx.x;
    finalize_coefs(t, sum, sumsq, gamma, beta, s_scale, s_shift);
    __syncthreads();
    const int local = blockIdx.x;          // 3136 blocks
    const int ch = local / GPB;
    const int gp = (local % GPB) * 256 + t;
    const int n = gp / HW, p = gp % HW;
    const short* base = y + (size_t)n * C * HW + p + (size_t)(ch * 16) * HW;
    int b0 = 0, b1 = 0, b2 = 0, b3 = 0;
#pragma unroll
    for (int e = 0; e < 16; ++e) {
        const int c = ch * 16 + e;
        float z = (float)base[(size_t)e * HW] * s_scale[c] + s_shift[c];
        int b = (z < 0.f) ? 0xFF : 0x01;
        int sh = (e & 3) * 8;
        if (e < 4) b0 |= b << sh; else if (e < 8) b1 |= b << sh;
        else if (e < 12) b2 |= b << sh; else b3 |= b << sh;
    }
    v4i o; o.x = b0; o.y = b1; o.z = b2; o.w = b3;
    xb[(size_t)ch * GP + gp] = o;
}

// ---------------------------------------------------------------------------
// R13 bconv: MT=112 (7 m-tiles). R12 post-mortem refuted boundary-overhead;
// conv residue = 16-MFMA cluster (~150cy) < L2 latency (~250cy) at ping-pong
// distance 1. 28-MFMA cluster (~270cy) covers it at the SAME distance; halo
// over-stage 2.0 -> 1.57x; B L2 traffic /1.75. Est ~240 VGPR, bounds(256,2).
// ---------------------------------------------------------------------------

#define ACCD(m) v4i c##m##_0={0,0,0,0}, c##m##_1={0,0,0,0}, \
                    c##m##_2={0,0,0,0}, c##m##_3={0,0,0,0};
#define ACC_DECL ACCD(0) ACCD(1) ACCD(2) ACCD(3) ACCD(4) ACCD(5) ACCD(6)

#define MFMA(a,b,c) c = __builtin_amdgcn_mfma_i32_16x16x64_i8(a, b, c, 0, 0, 0);

#define B_LOADQ(P, idx) { const v4i* bp = wbf + (idx); \
    P##0 = bp[0]; P##1 = bp[64]; P##2 = bp[128]; P##3 = bp[192]; }

#define ARD(P, m, cb) P##m = xl[R##m + ((cb) ^ S##m)];
#define ARDALL(P, cb) ARD(P,0,cb) ARD(P,1,cb) ARD(P,2,cb) ARD(P,3,cb) \
                      ARD(P,4,cb) ARD(P,5,cb) ARD(P,6,cb)

#define MFMAG(A,B,g) MFMA(A##0,B##g,c0_##g) MFMA(A##1,B##g,c1_##g) MFMA(A##2,B##g,c2_##g) \
                     MFMA(A##3,B##g,c3_##g) MFMA(A##4,B##g,c4_##g) MFMA(A##5,B##g,c5_##g) \
                     MFMA(A##6,B##g,c6_##g)
#define MFMA_C(A,B) __builtin_amdgcn_s_setprio(1); \
    MFMAG(A,B,0) MFMAG(A,B,1) MFMAG(A,B,2) MFMAG(A,B,3) \
    __builtin_amdgcn_s_setprio(0);

// per-m-tile mask + row select (row = lrb + 16m keeps low4 bits = sm)
#define TV1(m) { const bool mk = ((unsigned)(cm##m + dc) < 28u) && \
                                 ((unsigned)(rm##m + dr) < 28u); \
    R##m = mk ? (lrb + 16 * (m)) * 16 : ZROW; S##m = mk ? sm : 0; }
#define TAPVARS(TPX) { const int dr = (TPX)/3 - 1, dc = (TPX)%3 - 1; \
    const int lrb = 32 + llo + dr * W + dc; const int sm = lrb & 15; \
    TV1(0) TV1(1) TV1(2) TV1(3) TV1(4) TV1(5) TV1(6) }

#define PMV(m) const int gx##m = gp0 + (m)*16 + llo; \
    const int pmv##m = gx##m % HW; \
    const int rm##m = pmv##m / W, cm##m = pmv##m % W;

#define EPIV(m,g) { \
    const int gpv = gp0 + (m)*16 + lhi*4; \
    const int nn = gpv / HW; const int pp = gpv - nn*HW; \
    const size_t base = (size_t)nn*(C*HW) + (size_t)(wn*64+(g)*16+llo)*HW + pp; \
    const v4i cc = c##m##_##g; \
    if constexpr (HAS_RES) { \
        const float4 r = *(const float4*)(residual + base); \
        float4 o; o.x = (float)cc.x + r.x; o.y = (float)cc.y + r.y; \
        o.z = (float)cc.z + r.z; o.w = (float)cc.w + r.w; \
        *(float4*)((float*)yout + base) = o; \
        sy##g += o.x + o.y + o.z + o.w; \
        sq##g += o.x*o.x + o.y*o.y + o.z*o.z + o.w*o.w; \
    } else { \
        int2 o; o.x = (cc.x & 0xFFFF) | (cc.y << 16); \
        o.y = (cc.z & 0xFFFF) | (cc.w << 16); \
        *(int2*)((short*)yout + base) = o; \
        const float fx = (float)cc.x, fy = (float)cc.y, fz = (float)cc.z, fw = (float)cc.w; \
        sy##g += fx + fy + fz + fw; \
        sq##g += fx*fx + fy*fy + fz*fz + fw*fw; \
    } }
#define EPIM(m) EPIV(m,0) EPIV(m,1) EPIV(m,2) EPIV(m,3)

#define REDN(g) { float s1 = sy##g, s2 = sq##g; \
    s1 += __shfl_down(s1, 32); s1 += __shfl_down(s1, 16); \
    s2 += __shfl_down(s2, 32); s2 += __shfl_down(s2, 16); \
    if (l < 16) { const int co = wn*64 + (g)*16 + l; \
        atomicAdd(&sum[co], (double)s1); atomicAdd(&sumsq[co], (double)s2); } }

template<bool HAS_RES, typename OUT_T>
__launch_bounds__(256, 2)
__global__ void bconv_mfma(const v4i* __restrict__ xb,
                           const v4i* __restrict__ wbf,
                           const float* __restrict__ residual,
                           OUT_T* __restrict__ yout,
                           double* __restrict__ sum, double* __restrict__ sumsq) {
    __shared__ v4i xl[LROWS * 16 + 16];     // 176 data rows + zero row (45.3 KB)
    const int t   = threadIdx.x;
    const int gp0 = blockIdx.x * MT;

    // stage 176 rows x 16 chunks, coalesced reads, swizzled LDS writes
    for (int pass = 0; pass < 11; ++pass) {
        const int i = pass * 256 + t;
        const int c = i / LROWS;            // plane 0..15
        const int r = i - c * LROWS;        // local row 0..175
        int gsrc = min(max(gp0 - 32 + r, 0), GP - 1);
        xl[r * 16 + (c ^ (r & 15))] = xb[(size_t)c * GP + gsrc];
    }
    if (t < 16) { v4i z = {0,0,0,0}; xl[ZROW + t] = z; }   // zero row
    __syncthreads();

    const int l = t & 63, wn = t >> 6;
    const int llo = l & 15, lhi = l >> 4;

    PMV(0) PMV(1) PMV(2) PMV(3) PMV(4) PMV(5) PMV(6)

    ACC_DECL
    const int bw = wn * 256 + l;

    int R0,R1,R2,R3,R4,R5,R6, S0,S1,S2,S3,S4,S5,S6;
    TAPVARS(0)
    v4i bP0,bP1,bP2,bP3, bQ0,bQ1,bQ2,bQ3;
    v4i aP0,aP1,aP2,aP3,aP4,aP5,aP6, aQ0,aQ1,aQ2,aQ3,aQ4,aQ5,aQ6;
    B_LOADQ(bP, bw)                 // (tap0, kb0)
    ARDALL(aP, lhi)

#pragma unroll 1
    for (int tp = 0; tp < 9; ++tp) {
        const int tb = bw + tp * 4096;
        // kb0: prefetch (tp,1); compute (tp,0)
        B_LOADQ(bQ, tb + 1024)
        ARDALL(aQ, 4 + lhi)
        MFMA_C(aP, bP)
        // kb1: prefetch (tp,2); compute (tp,1)
        B_LOADQ(bP, tb + 2048)
        ARDALL(aP, 8 + lhi)
        MFMA_C(aQ, bQ)
        // kb2: prefetch (tp,3); compute (tp,2)
        B_LOADQ(bQ, tb + 3072)
        ARDALL(aQ, 12 + lhi)
        MFMA_C(aP, bP)
        // kb3: next-tap vars (overwrite R/S); prefetch (tp+1,0); compute (tp,3)
        const int tpn = (tp < 8) ? tp + 1 : 8;
        TAPVARS(tpn)
        B_LOADQ(bP, bw + tpn * 4096)
        ARDALL(aP, lhi)
        MFMA_C(aQ, bQ)
    }

    // ---- epilogue: vectorized store + per-channel stats ----
    float sy0 = 0, sy1 = 0, sy2 = 0, sy3 = 0;
    float sq0 = 0, sq1 = 0, sq2 = 0, sq3 = 0;
    EPIM(0) EPIM(1) EPIM(2) EPIM(3) EPIM(4) EPIM(5) EPIM(6)
    REDN(0) REDN(1) REDN(2) REDN(3)
}

// ---------------------------------------------------------------------------
// Final: fused finalize (redundant per block) + out = clip(z*s+b, -1, 1)
// ---------------------------------------------------------------------------
__global__ void bn_clip_kernel(const float4* __restrict__ z,
                               const double* __restrict__ sum,
                               const double* __restrict__ sumsq,
                               const float* __restrict__ gamma,
                               const float* __restrict__ beta,
                               float4* __restrict__ out) {
    __shared__ float s_scale[C], s_shift[C];
    const int t = threadIdx.x;
    finalize_coefs(t, sum, sumsq, gamma, beta, s_scale, s_shift);
    __syncthreads();
    for (int i = blockIdx.x * blockDim.x + t; i < TOTAL / 4;
         i += gridDim.x * blockDim.x) {
        int c = (i / (HW / 4)) & (C - 1);
        float s = s_scale[c], b = s_shift[c];
        float4 v = z[i];
        v.x = fminf(1.f, fmaxf(-1.f, v.x * s + b));
        v.y = fminf(1.f, fmaxf(-1.f, v.y * s + b));
        v.z = fminf(1.f, fmaxf(-1.f, v.z * s + b));
        v.w = fminf(1.f, fmaxf(-1.f, v.w * s + b));
        out[i] = v;
    }
}

// ---------------------------------------------------------------------------
extern "C" void kernel_launch(void* const* d_in, const int* in_sizes, int n_in,
                              void* d_out, int out_size, void* d_ws, size_t ws_size,
                              hipStream_t stream) {
    const float* x  = (const float*)d_in[0];
    const float* w1 = (const float*)d_in[1];
    const float* w2 = (const float*)d_in[2];
    const float* g1 = (const float*)d_in[3];
    const float* b1 = (const float*)d_in[4];
    const float* g2 = (const float*)d_in[5];
    const float* b2 = (const float*)d_in[6];
    float* out = (float*)d_out;

    char* ws = (char*)d_ws;
    size_t off = 0;
    float* z2 = (float*)(ws + off);   off += (size_t)TOTAL * 4;        // 51.4 MB
    v4i* xb1  = (v4i*)(ws + off);     off += (size_t)GP * 16 * 16;     // 12.85 MB
    v4i* xb2  = (v4i*)(ws + off);     off += (size_t)GP * 16 * 16;     // 12.85 MB
    v4i* wbf1 = (v4i*)(ws + off);     off += (size_t)36864 * 16;       // 590 KB
    v4i* wbf2 = (v4i*)(ws + off);     off += (size_t)36864 * 16;
    double* stats = (double*)(ws + off); off += 4 * 256 * 8;
    double* sum1 = stats, *sumsq1 = stats + 256, *sum2 = stats + 512, *sumsq2 = stats + 768;

    // y1 (i16) lives in d_out as scratch; fully rewritten by bn_clip at the end
    short* y1 = (short*)d_out;

    // pre-pass: weight packs (LDS-transpose, 32 blocks) + x pack + stats zero
    pack_all_kernel<<<32 + 16 * GPB, 256, 0, stream>>>(w1, w2, x, wbf1, wbf2, xb1, stats);

    // conv1: y1 (i16) -> d_out scratch, fused BN1 stats
    bconv_mfma<false, short><<<NBLK, 256, 0, stream>>>(xb1, wbf1, nullptr, y1, sum1, sumsq1);
    // finalize1 (inline) + BN1 + hardtanh + binarize -> i8 planes
    bn_signpack_kernel<<<16 * GPB, 256, 0, stream>>>(y1, sum1, sumsq1, g1, b1, xb2);
    // conv2 + residual, fused BN2 stats, z2 -> ws
    bconv_mfma<true, float><<<NBLK, 256, 0, stream>>>(xb2, wbf2, x, z2, sum2, sumsq2);
    // finalize2 (inline) + BN2 + hardtanh -> out
    bn_clip_kernel<<<4096, 256, 0, stream>>>((const float4*)z2, sum2, sumsq2, g2, b2,
                                             (float4*)out);
}